// Round 3
// baseline (500.877 us; speedup 1.0000x reference)
//
#include <hip/hip_runtime.h>

#define NCH    64
#define NPTS   16384
#define NS     16
#define QSCALE 0.125f

// v4: v3 + full load hoist and lgkmcnt-only barriers.
//
// v3 (~124us kernel): cost burst issued only AFTER 3 barriers + 2 LDS matvec
// phases; __syncthreads drains vmcnt(0) -> per-generation convoy: HBM idle
// during prologue, VALU idle during stream. 2x off the ~60us overlap ceiling.
//
// v4 changes:
//  - ALL global loads issue at the top in consumption order
//    [w_k, point, w_pos/b_pos, geom, cost]; prologue consumes early loads via
//    counted vmcnt while the 16KB/wave cost burst stays in flight.
//  - barriers are raw "s_waitcnt lgkmcnt(0); s_barrier" (all cross-thread
//    prologue data is LDS-only) -> no implicit vmcnt(0) drain.
//  - w_v^T staging moved to after PV (w_k half of wmat dead) so its loads
//    never force a cost drain.
//  - qp stored as [n][c2*16+g] (pitch 76): stream reads 4x ds_read_b128
//    instead of 16x ds_read_b32. All LDS patterns <=2-way except 4 one-time
//    writes.
#define BARRIER() asm volatile("s_waitcnt lgkmcnt(0)\n\ts_barrier" ::: "memory")

__global__ __launch_bounds__(256, 4) void pt_attn_kernel(
    const float* __restrict__ xyz,     // [B,3,N]
    const float* __restrict__ nxyz,    // [B,3,N,S]
    const float* __restrict__ point,   // [B,C,N]
    const float* __restrict__ cost,    // [B,C,N,S]
    const float* __restrict__ w_k,     // [C,C]
    const float* __restrict__ w_v,     // [C,C]
    const float* __restrict__ w_pos,   // [C,4]
    const float* __restrict__ b_pos,   // [C]
    float* __restrict__ out)           // [B,C,N]
{
    __shared__ float wmat[64][68];  // w_k[o][c]; after stream: w_v^T[c][o]
    __shared__ float ptq[64][16];   // point tile * QSCALE, [o][nl]
    __shared__ float qp2[16][76];   // qp2[nl][c2*16+g] = qp[c=4g+c2][n]
    __shared__ float wpb[5][65];    // w_pos^T[j][c] (j<4); b_pos[c] (j=4)
    __shared__ float qg[5][16];     // geometry coefs per point
    __shared__ float linit[4][64];  // per-wave logit init [w][n*16+s]
    __shared__ float wc[16][68];    // wc[nl][c] = sum_s attn*cost

    const int t  = threadIdx.x;
    const int b  = blockIdx.x >> 10;          // 1024 tiles per batch
    const int n0 = (blockIdx.x & 1023) << 4;  // 16 points per block

    const float* point_b = point + (size_t)b * NCH * NPTS;
    const float* cost_b  = cost  + (size_t)b * NCH * NPTS * NS;
    const float* xyz_b   = xyz   + (size_t)b * 3 * NPTS;
    const float* nxyz_b  = nxyz  + (size_t)b * 3 * NPTS * NS;
    float*       out_b   = out   + (size_t)b * NCH * NPTS;

    const int w    = __builtin_amdgcn_readfirstlane(t >> 6);  // wave 0..3
    const int lane = t & 63;

    // ========== all global loads, issued up front in consumption order ======
    // (a) w_k staging values (consumed first, region 0)
    float wkv[16];
#pragma unroll
    for (int i = 0; i < 16; ++i) wkv[i] = w_k[t + i * 256];
    // (b) point tile
    float ptv[4];
#pragma unroll
    for (int i = 0; i < 4; ++i) {
        int idx = t + i * 256;
        ptv[i] = point_b[(idx >> 4) * NPTS + n0 + (idx & 15)];
    }
    // (c) pos-encoding weights
    float wpv = w_pos[t & 255];
    float bpv = (t < 64) ? b_pos[t] : 0.f;
    // (d) geometry (consumed in stream, before cost)
    const int n0w = n0 + (w << 2);
    const int gn  = lane >> 4;         // geometry role: n 0..3
    const int gs  = lane & 15;         // geometry role: s 0..15
    float gx0 = xyz_b[0 * NPTS + n0w + gn];
    float gx1 = xyz_b[1 * NPTS + n0w + gn];
    float gx2 = xyz_b[2 * NPTS + n0w + gn];
    float ga0 = nxyz_b[(size_t)(0 * NPTS + n0w + gn) * NS + gs];
    float ga1 = nxyz_b[(size_t)(1 * NPTS + n0w + gn) * NS + gs];
    float ga2 = nxyz_b[(size_t)(2 * NPTS + n0w + gn) * NS + gs];
    // (e) the wave's whole cost tile: 16 x dwordx4 = 16KB, all in flight.
    const int c2 = lane >> 4;          // c-group 0..3
    const int nn = (lane >> 2) & 3;    // point-in-wave 0..3
    const int s4 = lane & 3;           // s-quad 0..3
    const float4* cbase = (const float4*)(cost_b + (size_t)(n0w + nn) * NS) + s4;
    float4 cr[16];
#pragma unroll
    for (int g = 0; g < 16; ++g)
        cr[g] = cbase[(size_t)(g * 4 + c2) * NPTS * 4];

    // ---- region 0: stage w_k, scaled point tile, w_pos^T/b_pos ----
#pragma unroll
    for (int i = 0; i < 16; ++i) {
        int idx = t + i * 256;
        wmat[idx >> 6][idx & 63] = wkv[i];   // per wave: row uniform, 2-way
    }
#pragma unroll
    for (int i = 0; i < 4; ++i) {
        int idx = t + i * 256;
        ptq[idx >> 4][idx & 15] = ptv[i] * QSCALE;
    }
    wpb[t & 3][t >> 2] = wpv;                // [C,4] -> [j][c]
    if (t < 64) wpb[4][t] = bpv;
    BARRIER();

    // ---- region 1: qp[c=4*cg+k][nl] = sum_o w_k[o][c] * ptq[o][nl] ----
    {
        const int nl = t & 15, cg = t >> 4;  // cg 0..15
        float a0 = 0.f, a1 = 0.f, a2 = 0.f, a3 = 0.f;
#pragma unroll 8
        for (int o = 0; o < NCH; ++o) {
            float pvv = ptq[o][nl];                          // bcast, free
            float4 wk = *(const float4*)&wmat[o][cg * 4];    // b128, free
            a0 = fmaf(wk.x, pvv, a0);
            a1 = fmaf(wk.y, pvv, a1);
            a2 = fmaf(wk.z, pvv, a2);
            a3 = fmaf(wk.w, pvv, a3);
        }
        // qp2[nl][c2*16+g]: c = cg*4+k -> c2=k, g=cg
        qp2[nl][0 * 16 + cg] = a0;           // 4 b32 writes, <=2-way
        qp2[nl][1 * 16 + cg] = a1;
        qp2[nl][2 * 16 + cg] = a2;
        qp2[nl][3 * 16 + cg] = a3;
    }
    BARRIER();

    // ---- region 2: qg[j][n] = sum_c qp[c][n]*w_pos[c][j] (+ b_pos dot) ----
    if (t < 80) {
        const int j = t >> 4, nl = t & 15;   // j 0..4
        float a = 0.f;
#pragma unroll 8
        for (int c = 0; c < NCH; ++c)
            a = fmaf(qp2[nl][(c & 3) * 16 + (c >> 2)], wpb[j][c], a);
        qg[j][nl] = a;                       // qg[4] = qp . b_pos
    }
    BARRIER();

    // ================= stream phase (no barriers, cost in regs) ============
    // logit geometry init, bounced through LDS into the (c2,nn,s4) layout.
    {
        float t0 = gx0 - ga0, t1 = gx1 - ga1, t2 = gx2 - ga2;
        float nr = sqrtf(fmaf(t0, t0, fmaf(t1, t1, t2 * t2)));
        int nlg = (w << 2) + gn;
        float li = fmaf(qg[0][nlg], t0, fmaf(qg[1][nlg], t1,
                   fmaf(qg[2][nlg], t2, fmaf(qg[3][nlg], nr, qg[4][nlg]))));
        linit[w][lane] = li;                 // same-wave write->read: in-order
    }
    float4 lg = *(const float4*)&linit[w][nn * 16 + s4 * 4];
    if (c2 != 0) { lg.x = 0.f; lg.y = 0.f; lg.z = 0.f; lg.w = 0.f; }

    // logits: this lane's 16 c's (c = 4g+c2); qp row read as 4 x b128
    const int nl = (w << 2) + nn;
    const float* qrow = &qp2[nl][c2 * 16];
#pragma unroll
    for (int k = 0; k < 4; ++k) {
        float4 qv = *(const float4*)(qrow + 4 * k);
        lg.x = fmaf(qv.x, cr[4 * k + 0].x, lg.x);
        lg.y = fmaf(qv.x, cr[4 * k + 0].y, lg.y);
        lg.z = fmaf(qv.x, cr[4 * k + 0].z, lg.z);
        lg.w = fmaf(qv.x, cr[4 * k + 0].w, lg.w);
        lg.x = fmaf(qv.y, cr[4 * k + 1].x, lg.x);
        lg.y = fmaf(qv.y, cr[4 * k + 1].y, lg.y);
        lg.z = fmaf(qv.y, cr[4 * k + 1].z, lg.z);
        lg.w = fmaf(qv.y, cr[4 * k + 1].w, lg.w);
        lg.x = fmaf(qv.z, cr[4 * k + 2].x, lg.x);
        lg.y = fmaf(qv.z, cr[4 * k + 2].y, lg.y);
        lg.z = fmaf(qv.z, cr[4 * k + 2].z, lg.z);
        lg.w = fmaf(qv.z, cr[4 * k + 2].w, lg.w);
        lg.x = fmaf(qv.w, cr[4 * k + 3].x, lg.x);
        lg.y = fmaf(qv.w, cr[4 * k + 3].y, lg.y);
        lg.z = fmaf(qv.w, cr[4 * k + 3].z, lg.z);
        lg.w = fmaf(qv.w, cr[4 * k + 3].w, lg.w);
    }
    // reduce over c-groups (lane bits 4-5)
    lg.x += __shfl_xor(lg.x, 16); lg.y += __shfl_xor(lg.y, 16);
    lg.z += __shfl_xor(lg.z, 16); lg.w += __shfl_xor(lg.w, 16);
    lg.x += __shfl_xor(lg.x, 32); lg.y += __shfl_xor(lg.y, 32);
    lg.z += __shfl_xor(lg.z, 32); lg.w += __shfl_xor(lg.w, 32);

    // softmax over S=16: 4 in-lane x 4 lanes (bits 0-1)
    float m = fmaxf(fmaxf(lg.x, lg.y), fmaxf(lg.z, lg.w));
    m = fmaxf(m, __shfl_xor(m, 1));
    m = fmaxf(m, __shfl_xor(m, 2));
    float4 at;
    at.x = __expf(lg.x - m); at.y = __expf(lg.y - m);
    at.z = __expf(lg.z - m); at.w = __expf(lg.w - m);
    float Z = at.x + at.y + at.z + at.w;
    Z += __shfl_xor(Z, 1);
    Z += __shfl_xor(Z, 2);
    float rz = 1.f / Z;
    at.x *= rz; at.y *= rz; at.z *= rz; at.w *= rz;

    // weighted value sum, from registers (cost's second use)
#pragma unroll
    for (int g = 0; g < 16; ++g) {
        float p = fmaf(at.x, cr[g].x, fmaf(at.y, cr[g].y,
                  fmaf(at.z, cr[g].z, at.w * cr[g].w)));
        p += __shfl_xor(p, 1);
        p += __shfl_xor(p, 2);
        if (s4 == 0) wc[nl][g * 4 + c2] = p;   // 16 lanes, 16 banks: free
    }

    // stage w_v^T into wmat (w_k half dead since region 1; all waves past
    // BARRIER 2). Loads issue after cost in FIFO but are consumed after the
    // stream -> no forced cost drain anywhere.
#pragma unroll
    for (int i = 0; i < 16; ++i) {
        int idx = t + i * 256;
        wmat[idx & 63][idx >> 6] = w_v[idx];   // transposed store, one-time
    }
    BARRIER();

    // ---- phase E: out[o][n] = sum_c w_v[o][c] * wc[c][n] ----
    {
        const int og = t >> 4, nlo = t & 15;
        float a0 = 0.f, a1 = 0.f, a2 = 0.f, a3 = 0.f;
#pragma unroll 8
        for (int c = 0; c < NCH; ++c) {
            float wcv = wc[nlo][c];                          // 2-way, free
            float4 wv = *(const float4*)&wmat[c][og * 4];    // b128, free
            a0 = fmaf(wv.x, wcv, a0);
            a1 = fmaf(wv.y, wcv, a1);
            a2 = fmaf(wv.z, wcv, a2);
            a3 = fmaf(wv.w, wcv, a3);
        }
        float* op = out_b + (size_t)(og * 4) * NPTS + n0 + nlo;
        op[0]        = a0;
        op[NPTS]     = a1;
        op[2 * NPTS] = a2;
        op[3 * NPTS] = a3;
    }
}

extern "C" void kernel_launch(void* const* d_in, const int* in_sizes, int n_in,
                              void* d_out, int out_size, void* d_ws, size_t ws_size,
                              hipStream_t stream) {
    const float* xyz   = (const float*)d_in[0];
    const float* nxyz  = (const float*)d_in[1];
    const float* point = (const float*)d_in[2];
    // d_in[3] = neighbor_points: unused by the reference computation
    const float* cost  = (const float*)d_in[4];
    const float* w_k   = (const float*)d_in[5];
    const float* w_v   = (const float*)d_in[6];
    const float* w_pos = (const float*)d_in[7];
    const float* b_pos = (const float*)d_in[8];
    float* outp = (float*)d_out;

    dim3 grid(4096), block(256);
    hipLaunchKernelGGL(pt_attn_kernel, grid, block, 0, stream,
                       xyz, nxyz, point, cost, w_k, w_v, w_pos, b_pos, outp);
}